// Round 1
// baseline (666.861 us; speedup 1.0000x reference)
//
#include <hip/hip_runtime.h>
#include <hip/hip_bf16.h>

typedef __bf16 bf16_t;
typedef bf16_t bf16x8 __attribute__((ext_vector_type(8)));
typedef bf16_t bf16x4v __attribute__((ext_vector_type(4)));
typedef float f32x4 __attribute__((ext_vector_type(4)));

// problem constants
static constexpr int EE = 1024;   // E
static constexpr int SS = 2048;   // S
static constexpr int DK = 64;

__device__ __forceinline__ void gload_lds16(const void* g, void* l) {
  __builtin_amdgcn_global_load_lds(
      (__attribute__((address_space(1))) void*)g,
      (__attribute__((address_space(3))) void*)l, 16, 0, 0);
}

__device__ __forceinline__ f32x4 mfma16(bf16x8 a, bf16x8 b, f32x4 c) {
  return __builtin_amdgcn_mfma_f32_16x16x32_bf16(a, b, c, 0, 0, 0);
}

// ---------------------------------------------------------------------------
// prep: x -> bf16, and quantum heads qh = cos(x + theta[d%64]) into A2 right
// half (A2 = [ctx | qh], row stride 2048).
// ---------------------------------------------------------------------------
__global__ void __launch_bounds__(256) prep_x_kernel(
    const float* __restrict__ x, const float* __restrict__ theta,
    bf16_t* __restrict__ xbf, bf16_t* __restrict__ A2)
{
  const long t = (long)blockIdx.x * 256 + threadIdx.x;
  const long e0 = t * 8;
  const int col = (int)(e0 & (EE - 1));
  const long row = e0 >> 10;
  const float4 v0 = *(const float4*)&x[e0];
  const float4 v1 = *(const float4*)&x[e0 + 4];
  float xs[8] = {v0.x, v0.y, v0.z, v0.w, v1.x, v1.y, v1.z, v1.w};
  const int d0 = col & (DK - 1);   // col multiple of 8 -> d0+j <= 63
  bf16x8 xb, qb;
#pragma unroll
  for (int j = 0; j < 8; ++j) {
    xb[j] = (bf16_t)xs[j];
    qb[j] = (bf16_t)__cosf(xs[j] + theta[d0 + j]);
  }
  *(bf16x8*)&xbf[e0] = xb;
  *(bf16x8*)&A2[row * 2048 + EE + col] = qb;
}

// ---------------------------------------------------------------------------
// weight transpose + f32->bf16: dst[n*dstride + dcol0 + k] = src[k*N + n]
// block (32,8); grid (N/32, K/32)
// ---------------------------------------------------------------------------
__global__ void __launch_bounds__(256) transpose_w_kernel(
    const float* __restrict__ src, bf16_t* __restrict__ dst,
    int N, long dstride, long dcol0)
{
  __shared__ float tile[32][33];
  const int tx = threadIdx.x, ty = threadIdx.y;
  const long n0 = (long)blockIdx.x * 32, k0 = (long)blockIdx.y * 32;
#pragma unroll
  for (int j = 0; j < 4; ++j)
    tile[ty + j * 8][tx] = src[(k0 + ty + j * 8) * N + n0 + tx];
  __syncthreads();
#pragma unroll
  for (int j = 0; j < 4; ++j)
    dst[(n0 + ty + j * 8) * dstride + dcol0 + k0 + tx] = (bf16_t)tile[tx][ty + j * 8];
}

// ---------------------------------------------------------------------------
// m97-structure GEMM: C[M,N] = A[M,K] * Bt[N,K]^T, bf16 in, f32 acc.
// 128x128 tile, BK=32, 256 thr = 4 waves (2x2), 16x16x32 MFMA, 4x4 frags/wave,
// global_load_lds width=16 staging, 2-phase barrier loop.
// MODE 0: C bf16 plain          (QKV)
// MODE 1: C f32 = 0.5*acc + aux1[row*N+col]            (attn-out + residual x)
// MODE 2: C bf16 = relu(acc + aux1[col])               (FFN1)
// MODE 3: C f32 = acc + aux1[col] + (f32)aux2[row*N+col]  (FFN2 + residual x1)
// ---------------------------------------------------------------------------
template<int MODE>
__global__ void __launch_bounds__(256, 3) gemm_bt(
    const bf16_t* __restrict__ A, const bf16_t* __restrict__ Bt,
    void* __restrict__ C, int M, int N, int K,
    const float* __restrict__ aux1, const bf16_t* __restrict__ aux2)
{
  __shared__ bf16_t As[128 * 32];
  __shared__ bf16_t Bs[128 * 32];
  const int tid = threadIdx.x;
  const int lane = tid & 63, wid = tid >> 6;
  const int wr = wid >> 1, wc = wid & 1;
  const int lr = lane & 15, lk = lane >> 4;
  const long m0 = (long)blockIdx.y * 128;
  const long n0 = (long)blockIdx.x * 128;
  f32x4 acc[4][4] = {};

  for (int k0 = 0; k0 < K; k0 += 32) {
#pragma unroll
    for (int j = 0; j < 2; ++j) {
      const int c = __builtin_amdgcn_readfirstlane(wid * 2 + j); // wave-uniform LDS base
      const int e = c * 512 + lane * 8;
      const int row = e >> 5, colk = e & 31;
      gload_lds16(&A[(m0 + row) * K + k0 + colk], &As[c * 512]);
      gload_lds16(&Bt[(n0 + row) * K + k0 + colk], &Bs[c * 512]);
    }
    __syncthreads();
    bf16x8 af[4], bfr[4];
#pragma unroll
    for (int mb = 0; mb < 4; ++mb)
      af[mb] = *(const bf16x8*)&As[(wr * 64 + mb * 16 + lr) * 32 + lk * 8];
#pragma unroll
    for (int nb = 0; nb < 4; ++nb)
      bfr[nb] = *(const bf16x8*)&Bs[(wc * 64 + nb * 16 + lr) * 32 + lk * 8];
#pragma unroll
    for (int mb = 0; mb < 4; ++mb)
#pragma unroll
      for (int nb = 0; nb < 4; ++nb)
        acc[mb][nb] = mfma16(af[mb], bfr[nb], acc[mb][nb]);
    __syncthreads();
  }

#pragma unroll
  for (int mb = 0; mb < 4; ++mb)
#pragma unroll
    for (int nb = 0; nb < 4; ++nb)
#pragma unroll
      for (int i = 0; i < 4; ++i) {
        const long r = m0 + wr * 64 + mb * 16 + lk * 4 + i;   // C row (m89 layout)
        const long cc = n0 + wc * 64 + nb * 16 + lr;          // C col
        const float v = acc[mb][nb][i];
        if constexpr (MODE == 0) {
          ((bf16_t*)C)[r * N + cc] = (bf16_t)v;
        } else if constexpr (MODE == 1) {
          ((float*)C)[r * N + cc] = 0.5f * v + aux1[r * N + cc];
        } else if constexpr (MODE == 2) {
          ((bf16_t*)C)[r * N + cc] = (bf16_t)fmaxf(v + aux1[cc], 0.0f);
        } else {
          ((float*)C)[r * N + cc] = v + aux1[cc] + (float)aux2[r * N + cc];
        }
      }
}

// ---------------------------------------------------------------------------
// flash attention: grid (64 = b*h, 16 q-tiles of 128). 256 thr = 4 waves,
// each wave owns 32 q-rows. KV tiles of 64. In-register wave-parallel online
// softmax (butterfly over 16-lane col groups), P bounced via padded LDS
// (stride 72 elems -> only 2-way bank aliasing, free per m136).
// QKV layout: [8192][3072] bf16 (q | k | v per row), scale 1/8 applied to S.
// ---------------------------------------------------------------------------
__global__ void __launch_bounds__(256, 2) attn_kernel(
    const bf16_t* __restrict__ QKV, bf16_t* __restrict__ Ctx)
{
  __shared__ bf16_t Qs[128 * 72];
  __shared__ bf16_t Ks[64 * 72];
  __shared__ bf16_t Vt[64 * 72];   // V transposed: Vt[d][kv]
  __shared__ bf16_t Ps[4 * 32 * 72];
  const int tid = threadIdx.x;
  const int lane = tid & 63, w = tid >> 6;
  const int lr = lane & 15, lk = lane >> 4;
  const int bh = blockIdx.x, b = bh >> 4, h = bh & 15;
  const long rowbase = (long)b * SS;
  const int q0 = blockIdx.y * 128;
  const int qcol = h * 64, kcol = EE + h * 64, vcol = 2 * EE + h * 64;

#pragma unroll
  for (int it = 0; it < 4; ++it) {
    const int e = tid * 8 + it * 2048;
    const int r = e >> 6, d = e & 63;
    *(bf16x8*)&Qs[r * 72 + d] =
        *(const bf16x8*)&QKV[(rowbase + q0 + r) * 3072 + qcol + d];
  }

  f32x4 oacc[2][4] = {};
  float mrow[2][4], lrow[2][4];
#pragma unroll
  for (int mb = 0; mb < 2; ++mb)
#pragma unroll
    for (int i = 0; i < 4; ++i) { mrow[mb][i] = -3.0e38f; lrow[mb][i] = 0.0f; }

  bf16_t* Pw = &Ps[w * 32 * 72];

  for (int kv0 = 0; kv0 < SS; kv0 += 64) {
    __syncthreads();   // all waves done with previous Ks/Vt
#pragma unroll
    for (int it = 0; it < 2; ++it) {
      const int e = tid * 8 + it * 2048;
      const int r = e >> 6, d = e & 63;
      *(bf16x8*)&Ks[r * 72 + d] =
          *(const bf16x8*)&QKV[(rowbase + kv0 + r) * 3072 + kcol + d];
      const bf16x8 vv = *(const bf16x8*)&QKV[(rowbase + kv0 + r) * 3072 + vcol + d];
#pragma unroll
      for (int jj = 0; jj < 8; ++jj) Vt[(d + jj) * 72 + r] = vv[jj];
    }
    __syncthreads();

    // S = Q K^T for this wave's 32 q-rows
    bf16x8 kf[4][2], qf[2][2];
#pragma unroll
    for (int nb = 0; nb < 4; ++nb)
#pragma unroll
      for (int ks = 0; ks < 2; ++ks)
        kf[nb][ks] = *(const bf16x8*)&Ks[(nb * 16 + lr) * 72 + ks * 32 + lk * 8];
#pragma unroll
    for (int mb = 0; mb < 2; ++mb)
#pragma unroll
      for (int ks = 0; ks < 2; ++ks)
        qf[mb][ks] = *(const bf16x8*)&Qs[(w * 32 + mb * 16 + lr) * 72 + ks * 32 + lk * 8];
    f32x4 sacc[2][4] = {};
#pragma unroll
    for (int mb = 0; mb < 2; ++mb)
#pragma unroll
      for (int nb = 0; nb < 4; ++nb)
#pragma unroll
        for (int ks = 0; ks < 2; ++ks)
          sacc[mb][nb] = mfma16(qf[mb][ks], kf[nb][ks], sacc[mb][nb]);

    // online softmax; lane holds rows lk*4+i, col lr+16*nb
#pragma unroll
    for (int mb = 0; mb < 2; ++mb) {
      float sv[4][4];
      float tmax[4] = {-3.0e38f, -3.0e38f, -3.0e38f, -3.0e38f};
#pragma unroll
      for (int nb = 0; nb < 4; ++nb)
#pragma unroll
        for (int i = 0; i < 4; ++i) {
          sv[nb][i] = sacc[mb][nb][i] * 0.125f;   // 1/sqrt(DK)
          tmax[i] = fmaxf(tmax[i], sv[nb][i]);
        }
#pragma unroll
      for (int i = 0; i < 4; ++i)
#pragma unroll
        for (int off = 1; off < 16; off <<= 1)
          tmax[i] = fmaxf(tmax[i], __shfl_xor(tmax[i], off));
      float mnew[4], resc[4], psum[4];
#pragma unroll
      for (int i = 0; i < 4; ++i) {
        mnew[i] = fmaxf(mrow[mb][i], tmax[i]);
        resc[i] = exp2f((mrow[mb][i] - mnew[i]) * 1.44269504f);
        mrow[mb][i] = mnew[i];
        psum[i] = 0.0f;
      }
      float p[4][4];
#pragma unroll
      for (int nb = 0; nb < 4; ++nb)
#pragma unroll
        for (int i = 0; i < 4; ++i) {
          p[nb][i] = exp2f((sv[nb][i] - mnew[i]) * 1.44269504f);
          psum[i] += p[nb][i];
        }
#pragma unroll
      for (int i = 0; i < 4; ++i) {
#pragma unroll
        for (int off = 1; off < 16; off <<= 1)
          psum[i] += __shfl_xor(psum[i], off);
        lrow[mb][i] = lrow[mb][i] * resc[i] + psum[i];
      }
#pragma unroll
      for (int nb = 0; nb < 4; ++nb)
#pragma unroll
        for (int i = 0; i < 4; ++i)
          oacc[mb][nb][i] *= resc[i];
#pragma unroll
      for (int nb = 0; nb < 4; ++nb)
#pragma unroll
        for (int i = 0; i < 4; ++i)
          Pw[(mb * 16 + lk * 4 + i) * 72 + nb * 16 + lr] = (bf16_t)p[nb][i];
    }

    // O += P V   (wave-private Pw write->read, no block barrier needed)
    bf16x8 vf[4][2], pf[2][2];
#pragma unroll
    for (int nb = 0; nb < 4; ++nb)
#pragma unroll
      for (int ks = 0; ks < 2; ++ks)
        vf[nb][ks] = *(const bf16x8*)&Vt[(nb * 16 + lr) * 72 + ks * 32 + lk * 8];
#pragma unroll
    for (int mb = 0; mb < 2; ++mb)
#pragma unroll
      for (int ks = 0; ks < 2; ++ks)
        pf[mb][ks] = *(const bf16x8*)&Pw[(mb * 16 + lr) * 72 + ks * 32 + lk * 8];
#pragma unroll
    for (int mb = 0; mb < 2; ++mb)
#pragma unroll
      for (int nb = 0; nb < 4; ++nb)
#pragma unroll
        for (int ks = 0; ks < 2; ++ks)
          oacc[mb][nb] = mfma16(pf[mb][ks], vf[nb][ks], oacc[mb][nb]);
  }

#pragma unroll
  for (int mb = 0; mb < 2; ++mb)
#pragma unroll
    for (int nb = 0; nb < 4; ++nb)
#pragma unroll
      for (int i = 0; i < 4; ++i) {
        const long r = rowbase + q0 + w * 32 + mb * 16 + lk * 4 + i;
        Ctx[r * 2048 + h * 64 + nb * 16 + lr] =
            (bf16_t)(oacc[mb][nb][i] / lrow[mb][i]);
      }
}

// ---------------------------------------------------------------------------
// LayerNorm over rows of 1024 f32; one block (256 thr) per row.
// ---------------------------------------------------------------------------
__device__ __forceinline__ void ln_reduce(const float4& v, int tid,
                                          float& mu, float& rs) {
  float s = v.x + v.y + v.z + v.w;
  float ss = v.x * v.x + v.y * v.y + v.z * v.z + v.w * v.w;
#pragma unroll
  for (int off = 1; off < 64; off <<= 1) {
    s += __shfl_xor(s, off);
    ss += __shfl_xor(ss, off);
  }
  __shared__ float wsum[4], wsq[4];
  if ((tid & 63) == 0) { wsum[tid >> 6] = s; wsq[tid >> 6] = ss; }
  __syncthreads();
  s = wsum[0] + wsum[1] + wsum[2] + wsum[3];
  ss = wsq[0] + wsq[1] + wsq[2] + wsq[3];
  mu = s * (1.0f / EE);
  rs = rsqrtf(ss * (1.0f / EE) - mu * mu + 1e-5f);
}

__global__ void __launch_bounds__(256) ln_bf16_kernel(
    const float* __restrict__ pre, const float* __restrict__ g,
    const float* __restrict__ bt, bf16_t* __restrict__ out)
{
  const int r = blockIdx.x, tid = threadIdx.x;
  const long base = (long)r * EE + tid * 4;
  const float4 v = *(const float4*)&pre[base];
  float mu, rs;
  ln_reduce(v, tid, mu, rs);
  const float4 gv = *(const float4*)&g[tid * 4];
  const float4 bv = *(const float4*)&bt[tid * 4];
  bf16x4v o;
  o[0] = (bf16_t)((v.x - mu) * rs * gv.x + bv.x);
  o[1] = (bf16_t)((v.y - mu) * rs * gv.y + bv.y);
  o[2] = (bf16_t)((v.z - mu) * rs * gv.z + bv.z);
  o[3] = (bf16_t)((v.w - mu) * rs * gv.w + bv.w);
  *(bf16x4v*)&out[base] = o;
}

__global__ void __launch_bounds__(256) ln_f32_kernel(
    const float* __restrict__ pre, const float* __restrict__ g,
    const float* __restrict__ bt, float* __restrict__ out)
{
  const int r = blockIdx.x, tid = threadIdx.x;
  const long base = (long)r * EE + tid * 4;
  const float4 v = *(const float4*)&pre[base];
  float mu, rs;
  ln_reduce(v, tid, mu, rs);
  const float4 gv = *(const float4*)&g[tid * 4];
  const float4 bv = *(const float4*)&bt[tid * 4];
  float4 o;
  o.x = (v.x - mu) * rs * gv.x + bv.x;
  o.y = (v.y - mu) * rs * gv.y + bv.y;
  o.z = (v.z - mu) * rs * gv.z + bv.z;
  o.w = (v.w - mu) * rs * gv.w + bv.w;
  *(float4*)&out[base] = o;
}

// ---------------------------------------------------------------------------
extern "C" void kernel_launch(void* const* d_in, const int* in_sizes, int n_in,
                              void* d_out, int out_size, void* d_ws, size_t ws_size,
                              hipStream_t stream)
{
  (void)in_sizes; (void)n_in; (void)out_size; (void)ws_size;
  const float* x     = (const float*)d_in[0];
  const float* Wq    = (const float*)d_in[1];
  const float* Wk    = (const float*)d_in[2];
  const float* Wv    = (const float*)d_in[3];
  const float* Wo    = (const float*)d_in[4];
  const float* theta = (const float*)d_in[5];
  const float* Wcq   = (const float*)d_in[6];
  const float* ln1g  = (const float*)d_in[7];
  const float* ln1b  = (const float*)d_in[8];
  const float* W1    = (const float*)d_in[9];
  const float* b1    = (const float*)d_in[10];
  const float* W2    = (const float*)d_in[11];
  const float* b2    = (const float*)d_in[12];
  const float* ln2g  = (const float*)d_in[13];
  const float* ln2b  = (const float*)d_in[14];

  // workspace layout (lifetime-aliased, 186 MB total)
  char* ws = (char*)d_ws;
  const size_t MB = 1ull << 20;
  bf16_t* xbf    = (bf16_t*)(ws + 0);          // 16MB: x bf16, later x1 (post-LN1)
  bf16_t* QKV    = (bf16_t*)(ws + 16 * MB);    // 48MB: q|k|v
  float*  preLN1 = (float*)(ws + 16 * MB);     // 32MB alias (QKV dead after attn)
  bf16_t* A2     = (bf16_t*)(ws + 64 * MB);    // 32MB: [ctx | qh]
  float*  preLN2 = (float*)(ws + 64 * MB);     // 32MB alias (A2 dead after gemm1)
  bf16_t* H1     = (bf16_t*)(ws + 96 * MB);    // 64MB: FFN hidden
  bf16_t* BtQKV  = (bf16_t*)(ws + 160 * MB);   // 6MB: [Wq;Wk;Wv]^T  [3072][1024]
  bf16_t* Bt2    = (bf16_t*)(ws + 166 * MB);   // 4MB: [Wo|Wcq]^T    [1024][2048]
  bf16_t* BtW1   = (bf16_t*)(ws + 170 * MB);   // 8MB: W1^T          [4096][1024]
  bf16_t* BtW2   = (bf16_t*)(ws + 178 * MB);   // 8MB: W2^T          [1024][4096]

  dim3 tb(32, 8);
  prep_x_kernel<<<4096, 256, 0, stream>>>(x, theta, xbf, A2);
  transpose_w_kernel<<<dim3(32, 32), tb, 0, stream>>>(Wq,  BtQKV,              1024, 1024, 0);
  transpose_w_kernel<<<dim3(32, 32), tb, 0, stream>>>(Wk,  BtQKV + 1024*1024,  1024, 1024, 0);
  transpose_w_kernel<<<dim3(32, 32), tb, 0, stream>>>(Wv,  BtQKV + 2048*1024,  1024, 1024, 0);
  transpose_w_kernel<<<dim3(32, 32), tb, 0, stream>>>(Wo,  Bt2,  1024, 2048, 0);
  transpose_w_kernel<<<dim3(32, 32), tb, 0, stream>>>(Wcq, Bt2,  1024, 2048, 1024);
  transpose_w_kernel<<<dim3(128, 32), tb, 0, stream>>>(W1, BtW1, 4096, 1024, 0);
  transpose_w_kernel<<<dim3(32, 128), tb, 0, stream>>>(W2, BtW2, 1024, 4096, 0);

  // 1) QKV projection
  gemm_bt<0><<<dim3(24, 64), 256, 0, stream>>>(xbf, BtQKV, QKV, 8192, 3072, 1024, nullptr, nullptr);
  // 2) flash attention -> ctx (left half of A2)
  attn_kernel<<<dim3(64, 16), 256, 0, stream>>>(QKV, A2);
  // 3) fused attn-out: 0.5*([ctx|qh] @ [Wo;Wcq]) + x -> preLN1
  gemm_bt<1><<<dim3(8, 64), 256, 0, stream>>>(A2, Bt2, preLN1, 8192, 1024, 2048, x, nullptr);
  // 4) LN1 -> x1 (bf16)
  ln_bf16_kernel<<<8192, 256, 0, stream>>>(preLN1, ln1g, ln1b, xbf);
  // 5) FFN1: relu(x1@W1 + b1) -> H1
  gemm_bt<2><<<dim3(32, 64), 256, 0, stream>>>(xbf, BtW1, H1, 8192, 4096, 1024, b1, nullptr);
  // 6) FFN2: H1@W2 + b2 + x1 -> preLN2
  gemm_bt<3><<<dim3(8, 64), 256, 0, stream>>>(H1, BtW2, preLN2, 8192, 1024, 4096, b2, xbf);
  // 7) LN2 -> output (f32)
  ln_f32_kernel<<<8192, 256, 0, stream>>>(preLN2, ln2g, ln2b, (float*)d_out);
}

// Round 2
// 554.316 us; speedup vs baseline: 1.2030x; 1.2030x over previous
//
#include <hip/hip_runtime.h>
#include <hip/hip_bf16.h>

typedef __bf16 bf16_t;
typedef bf16_t bf16x8 __attribute__((ext_vector_type(8)));
typedef bf16_t bf16x4v __attribute__((ext_vector_type(4)));
typedef float f32x4 __attribute__((ext_vector_type(4)));

// problem constants
static constexpr int EE = 1024;   // E
static constexpr int SS = 2048;   // S
static constexpr int DK = 64;

__device__ __forceinline__ void gload_lds16(const void* g, void* l) {
  __builtin_amdgcn_global_load_lds(
      (__attribute__((address_space(1))) void*)g,
      (__attribute__((address_space(3))) void*)l, 16, 0, 0);
}

__device__ __forceinline__ f32x4 mfma16(bf16x8 a, bf16x8 b, f32x4 c) {
  return __builtin_amdgcn_mfma_f32_16x16x32_bf16(a, b, c, 0, 0, 0);
}

// ---------------------------------------------------------------------------
// prep: x -> bf16, and quantum heads qh = cos(x + theta[d%64]) into A2 right
// half (A2 = [ctx | qh], row stride 2048).
// ---------------------------------------------------------------------------
__global__ void __launch_bounds__(256) prep_x_kernel(
    const float* __restrict__ x, const float* __restrict__ theta,
    bf16_t* __restrict__ xbf, bf16_t* __restrict__ A2)
{
  const long t = (long)blockIdx.x * 256 + threadIdx.x;
  const long e0 = t * 8;
  const int col = (int)(e0 & (EE - 1));
  const long row = e0 >> 10;
  const float4 v0 = *(const float4*)&x[e0];
  const float4 v1 = *(const float4*)&x[e0 + 4];
  float xs[8] = {v0.x, v0.y, v0.z, v0.w, v1.x, v1.y, v1.z, v1.w};
  const int d0 = col & (DK - 1);   // col multiple of 8 -> d0+j <= 63
  bf16x8 xb, qb;
#pragma unroll
  for (int j = 0; j < 8; ++j) {
    xb[j] = (bf16_t)xs[j];
    qb[j] = (bf16_t)__cosf(xs[j] + theta[d0 + j]);
  }
  *(bf16x8*)&xbf[e0] = xb;
  *(bf16x8*)&A2[row * 2048 + EE + col] = qb;
}

// ---------------------------------------------------------------------------
// weight transpose + f32->bf16: dst[n*dstride + dcol0 + k] = src[k*N + n]
// block (32,8); grid (N/32, K/32)
// ---------------------------------------------------------------------------
__global__ void __launch_bounds__(256) transpose_w_kernel(
    const float* __restrict__ src, bf16_t* __restrict__ dst,
    int N, long dstride, long dcol0)
{
  __shared__ float tile[32][33];
  const int tx = threadIdx.x, ty = threadIdx.y;
  const long n0 = (long)blockIdx.x * 32, k0 = (long)blockIdx.y * 32;
#pragma unroll
  for (int j = 0; j < 4; ++j)
    tile[ty + j * 8][tx] = src[(k0 + ty + j * 8) * N + n0 + tx];
  __syncthreads();
#pragma unroll
  for (int j = 0; j < 4; ++j)
    dst[(n0 + ty + j * 8) * dstride + dcol0 + k0 + tx] = (bf16_t)tile[tx][ty + j * 8];
}

// ---------------------------------------------------------------------------
// m97-structure GEMM: C[M,N] = A[M,K] * Bt[N,K]^T, bf16 in, f32 acc.
// 128x128 tile, BK=32, 256 thr = 4 waves (2x2), 16x16x32 MFMA, 4x4 frags/wave,
// global_load_lds width=16 staging, 2-phase barrier loop.
// MODE 0: C bf16 plain          (QKV)
// MODE 1: C f32 = 0.5*acc + aux1[row*N+col]            (attn-out + residual x)
// MODE 2: C bf16 = relu(acc + aux1[col])               (FFN1)
// MODE 3: C f32 = acc + aux1[col] + (f32)aux2[row*N+col]  (FFN2 + residual x1)
// ---------------------------------------------------------------------------
template<int MODE>
__global__ void __launch_bounds__(256, 3) gemm_bt(
    const bf16_t* __restrict__ A, const bf16_t* __restrict__ Bt,
    void* __restrict__ C, int M, int N, int K,
    const float* __restrict__ aux1, const bf16_t* __restrict__ aux2)
{
  __shared__ bf16_t As[128 * 32];
  __shared__ bf16_t Bs[128 * 32];
  const int tid = threadIdx.x;
  const int lane = tid & 63, wid = tid >> 6;
  const int wr = wid >> 1, wc = wid & 1;
  const int lr = lane & 15, lk = lane >> 4;
  const long m0 = (long)blockIdx.y * 128;
  const long n0 = (long)blockIdx.x * 128;
  f32x4 acc[4][4] = {};

  for (int k0 = 0; k0 < K; k0 += 32) {
#pragma unroll
    for (int j = 0; j < 2; ++j) {
      const int c = __builtin_amdgcn_readfirstlane(wid * 2 + j); // wave-uniform LDS base
      const int e = c * 512 + lane * 8;
      const int row = e >> 5, colk = e & 31;
      gload_lds16(&A[(m0 + row) * K + k0 + colk], &As[c * 512]);
      gload_lds16(&Bt[(n0 + row) * K + k0 + colk], &Bs[c * 512]);
    }
    __syncthreads();
    bf16x8 af[4], bfr[4];
#pragma unroll
    for (int mb = 0; mb < 4; ++mb)
      af[mb] = *(const bf16x8*)&As[(wr * 64 + mb * 16 + lr) * 32 + lk * 8];
#pragma unroll
    for (int nb = 0; nb < 4; ++nb)
      bfr[nb] = *(const bf16x8*)&Bs[(wc * 64 + nb * 16 + lr) * 32 + lk * 8];
#pragma unroll
    for (int mb = 0; mb < 4; ++mb)
#pragma unroll
      for (int nb = 0; nb < 4; ++nb)
        acc[mb][nb] = mfma16(af[mb], bfr[nb], acc[mb][nb]);
    __syncthreads();
  }

#pragma unroll
  for (int mb = 0; mb < 4; ++mb)
#pragma unroll
    for (int nb = 0; nb < 4; ++nb)
#pragma unroll
      for (int i = 0; i < 4; ++i) {
        const long r = m0 + wr * 64 + mb * 16 + lk * 4 + i;   // C row (m89 layout)
        const long cc = n0 + wc * 64 + nb * 16 + lr;          // C col
        const float v = acc[mb][nb][i];
        if constexpr (MODE == 0) {
          ((bf16_t*)C)[r * N + cc] = (bf16_t)v;
        } else if constexpr (MODE == 1) {
          ((float*)C)[r * N + cc] = 0.5f * v + aux1[r * N + cc];
        } else if constexpr (MODE == 2) {
          ((bf16_t*)C)[r * N + cc] = (bf16_t)fmaxf(v + aux1[cc], 0.0f);
        } else {
          ((float*)C)[r * N + cc] = v + aux1[cc] + (float)aux2[r * N + cc];
        }
      }
}

// ---------------------------------------------------------------------------
// flash attention v2: grid (64 = b*h, 16 q-tiles of 128). 256 thr = 4 waves,
// each wave owns 32 q-rows. KV tiles of 64, double-buffered LDS, async-split
// staging (issue loads for t+1, barrier, compute t, reg->LDS write t+1).
//
// Swapped QK^T: sacc = mfma(Kfrag, Qfrag) = S^T, so each lane owns ONE q-row
// (q = 16mb + lr) with k-local values {16nb + 4lk + i}. Softmax reduce =
// in-lane + shfl_xor(16) + shfl_xor(32). P written to per-wave LDS as packed
// b64 (conflict-free), re-read as b128 A-fragments for PV.
//
// Vt (V^T) uses a block-rotation swizzle to make the transpose scatter
// conflict-free: byte = d*144 + (((k>>3) + (d>>3)) & 7)*16 + (k&7)*2.
// ---------------------------------------------------------------------------
__global__ void __launch_bounds__(256, 2) attn_kernel(
    const bf16_t* __restrict__ QKV, bf16_t* __restrict__ Ctx)
{
  __shared__ bf16_t Ks[2][64 * 72];
  __shared__ bf16_t Vt[2][64 * 72];
  __shared__ bf16_t Ps[4][32 * 72];
  const int tid = threadIdx.x;
  const int lane = tid & 63, w = tid >> 6;
  const int lr = lane & 15, lk = lane >> 4;
  const int bh = blockIdx.x, b = bh >> 4, h = bh & 15;
  const long rowbase = (long)b * SS;
  const int q0 = blockIdx.y * 128;
  const int qcol = h * 64, kcol = EE + h * 64, vcol = 2 * EE + h * 64;
  constexpr int NT = SS / 64;   // 32 kv tiles

  // Q fragments straight to registers (read once)
  bf16x8 qf[2][2];
#pragma unroll
  for (int mb = 0; mb < 2; ++mb)
#pragma unroll
    for (int ks = 0; ks < 2; ++ks)
      qf[mb][ks] = *(const bf16x8*)&QKV[
          (rowbase + q0 + w * 32 + mb * 16 + lr) * 3072 + qcol + ks * 32 + lk * 8];

  // staging geometry: each thread loads 2x bf16x8 of K and of V
  const int sr = tid >> 3;        // k-row 0..31 (+32 for it=1)
  const int g  = tid & 7;         // d-block 0..7
  const int d0 = g * 8;

  bf16x8 kreg[2], vreg[2];
  auto load_kv = [&](int t) {
#pragma unroll
    for (int it = 0; it < 2; ++it) {
      const long r = rowbase + (long)t * 64 + sr + it * 32;
      kreg[it] = *(const bf16x8*)&QKV[r * 3072 + kcol + d0];
      vreg[it] = *(const bf16x8*)&QKV[r * 3072 + vcol + d0];
    }
  };
  auto write_kv = [&](int buf) {
#pragma unroll
    for (int it = 0; it < 2; ++it) {
      const int r = sr + it * 32;
      *(bf16x8*)&Ks[buf][r * 72 + d0] = kreg[it];
      // rotation-swizzled V^T scatter: elem = (d0+jj)*72 + blk*8 + (r&7),
      // blk = ((r>>3) + g) & 7   (note (d0+jj)>>3 == g since jj<8)
      const int vbase = d0 * 72 + (((r >> 3) + g) & 7) * 8 + (r & 7);
#pragma unroll
      for (int jj = 0; jj < 8; ++jj)
        Vt[buf][vbase + jj * 72] = vreg[it][jj];
    }
  };

  f32x4 oacc[2][4] = {};
  float mrow[2] = {-3.0e38f, -3.0e38f};
  float lrow[2] = {0.0f, 0.0f};
  bf16_t* Pw = &Ps[w][0];
  constexpr float LOG2E = 1.44269504f;

  load_kv(0);
  write_kv(0);

  for (int t = 0; t < NT; ++t) {
    const int buf = t & 1;
    if (t + 1 < NT) load_kv(t + 1);   // issue early; latency hides under compute
    __syncthreads();                  // buf ready; prior tile's readers done

    // fragments for this tile
    bf16x8 kf[4][2], vf[4][2];
#pragma unroll
    for (int nb = 0; nb < 4; ++nb)
#pragma unroll
      for (int ks = 0; ks < 2; ++ks) {
        kf[nb][ks] = *(const bf16x8*)&Ks[buf][(nb * 16 + lr) * 72 + ks * 32 + lk * 8];
        const int dvr = nb * 16 + lr;
        vf[nb][ks] = *(const bf16x8*)&Vt[buf][dvr * 72 + (((ks * 4 + lk) + (dvr >> 3)) & 7) * 8];
      }

    // S^T = mfma(K, Q): lane (lk,lr) holds S[k=16nb+4lk+i][q=16mb+lr]
    f32x4 sacc[2][4] = {};
    __builtin_amdgcn_s_setprio(1);
#pragma unroll
    for (int mb = 0; mb < 2; ++mb)
#pragma unroll
      for (int nb = 0; nb < 4; ++nb)
#pragma unroll
        for (int ks = 0; ks < 2; ++ks)
          sacc[mb][nb] = mfma16(kf[nb][ks], qf[mb][ks], sacc[mb][nb]);
    __builtin_amdgcn_s_setprio(0);

    // online softmax, one q-row per lane
#pragma unroll
    for (int mb = 0; mb < 2; ++mb) {
      float sv[4][4];
      float tmax = -3.0e38f;
#pragma unroll
      for (int nb = 0; nb < 4; ++nb)
#pragma unroll
        for (int i = 0; i < 4; ++i) {
          sv[nb][i] = sacc[mb][nb][i] * 0.125f;   // 1/sqrt(DK)
          tmax = fmaxf(tmax, sv[nb][i]);
        }
      tmax = fmaxf(tmax, __shfl_xor(tmax, 16));
      tmax = fmaxf(tmax, __shfl_xor(tmax, 32));
      const float mnew = fmaxf(mrow[mb], tmax);
      const float resc = exp2f((mrow[mb] - mnew) * LOG2E);
      mrow[mb] = mnew;
      float psum = 0.0f;
      float p[4][4];
#pragma unroll
      for (int nb = 0; nb < 4; ++nb)
#pragma unroll
        for (int i = 0; i < 4; ++i) {
          p[nb][i] = exp2f((sv[nb][i] - mnew) * LOG2E);
          psum += p[nb][i];
        }
      psum += __shfl_xor(psum, 16);
      psum += __shfl_xor(psum, 32);
      lrow[mb] = lrow[mb] * resc + psum;
      // packed b64 P writes: row q=16mb+lr, cols 16nb+4lk+0..3 (conflict-free)
#pragma unroll
      for (int nb = 0; nb < 4; ++nb) {
        bf16x4v pk;
#pragma unroll
        for (int i = 0; i < 4; ++i) pk[i] = (bf16_t)p[nb][i];
        *(bf16x4v*)&Pw[(mb * 16 + lr) * 72 + nb * 16 + lk * 4] = pk;
      }
      // redistribute rescale factor (keyed by lr) to C-layout rows (lk*4+i)
      float ro[4];
#pragma unroll
      for (int i = 0; i < 4; ++i) ro[i] = __shfl(resc, lk * 4 + i);
#pragma unroll
      for (int nb = 0; nb < 4; ++nb)
#pragma unroll
        for (int i = 0; i < 4; ++i)
          oacc[mb][nb][i] *= ro[i];
    }

    // O += P V  (wave-private Pw; same-wave write->read ordering via lgkmcnt)
    bf16x8 pf[2][2];
#pragma unroll
    for (int mb = 0; mb < 2; ++mb)
#pragma unroll
      for (int ks = 0; ks < 2; ++ks)
        pf[mb][ks] = *(const bf16x8*)&Pw[(mb * 16 + lr) * 72 + ks * 32 + lk * 8];
    __builtin_amdgcn_s_setprio(1);
#pragma unroll
    for (int mb = 0; mb < 2; ++mb)
#pragma unroll
      for (int nb = 0; nb < 4; ++nb)
#pragma unroll
        for (int ks = 0; ks < 2; ++ks)
          oacc[mb][nb] = mfma16(pf[mb][ks], vf[nb][ks], oacc[mb][nb]);
    __builtin_amdgcn_s_setprio(0);

    if (t + 1 < NT) write_kv((t + 1) & 1);   // write-late into the other buffer
  }

#pragma unroll
  for (int mb = 0; mb < 2; ++mb) {
    float li[4];
#pragma unroll
    for (int i = 0; i < 4; ++i) li[i] = 1.0f / __shfl(lrow[mb], lk * 4 + i);
#pragma unroll
    for (int nb = 0; nb < 4; ++nb)
#pragma unroll
      for (int i = 0; i < 4; ++i) {
        const long r = rowbase + q0 + w * 32 + mb * 16 + lk * 4 + i;
        Ctx[r * 2048 + h * 64 + nb * 16 + lr] = (bf16_t)(oacc[mb][nb][i] * li[i]);
      }
  }
}

// ---------------------------------------------------------------------------
// LayerNorm over rows of 1024 f32; one block (256 thr) per row.
// ---------------------------------------------------------------------------
__device__ __forceinline__ void ln_reduce(const float4& v, int tid,
                                          float& mu, float& rs) {
  float s = v.x + v.y + v.z + v.w;
  float ss = v.x * v.x + v.y * v.y + v.z * v.z + v.w * v.w;
#pragma unroll
  for (int off = 1; off < 64; off <<= 1) {
    s += __shfl_xor(s, off);
    ss += __shfl_xor(ss, off);
  }
  __shared__ float wsum[4], wsq[4];
  if ((tid & 63) == 0) { wsum[tid >> 6] = s; wsq[tid >> 6] = ss; }
  __syncthreads();
  s = wsum[0] + wsum[1] + wsum[2] + wsum[3];
  ss = wsq[0] + wsq[1] + wsq[2] + wsq[3];
  mu = s * (1.0f / EE);
  rs = rsqrtf(ss * (1.0f / EE) - mu * mu + 1e-5f);
}

__global__ void __launch_bounds__(256) ln_bf16_kernel(
    const float* __restrict__ pre, const float* __restrict__ g,
    const float* __restrict__ bt, bf16_t* __restrict__ out)
{
  const int r = blockIdx.x, tid = threadIdx.x;
  const long base = (long)r * EE + tid * 4;
  const float4 v = *(const float4*)&pre[base];
  float mu, rs;
  ln_reduce(v, tid, mu, rs);
  const float4 gv = *(const float4*)&g[tid * 4];
  const float4 bv = *(const float4*)&bt[tid * 4];
  bf16x4v o;
  o[0] = (bf16_t)((v.x - mu) * rs * gv.x + bv.x);
  o[1] = (bf16_t)((v.y - mu) * rs * gv.y + bv.y);
  o[2] = (bf16_t)((v.z - mu) * rs * gv.z + bv.z);
  o[3] = (bf16_t)((v.w - mu) * rs * gv.w + bv.w);
  *(bf16x4v*)&out[base] = o;
}

__global__ void __launch_bounds__(256) ln_f32_kernel(
    const float* __restrict__ pre, const float* __restrict__ g,
    const float* __restrict__ bt, float* __restrict__ out)
{
  const int r = blockIdx.x, tid = threadIdx.x;
  const long base = (long)r * EE + tid * 4;
  const float4 v = *(const float4*)&pre[base];
  float mu, rs;
  ln_reduce(v, tid, mu, rs);
  const float4 gv = *(const float4*)&g[tid * 4];
  const float4 bv = *(const float4*)&bt[tid * 4];
  float4 o;
  o.x = (v.x - mu) * rs * gv.x + bv.x;
  o.y = (v.y - mu) * rs * gv.y + bv.y;
  o.z = (v.z - mu) * rs * gv.z + bv.z;
  o.w = (v.w - mu) * rs * gv.w + bv.w;
  *(float4*)&out[base] = o;
}

// ---------------------------------------------------------------------------
extern "C" void kernel_launch(void* const* d_in, const int* in_sizes, int n_in,
                              void* d_out, int out_size, void* d_ws, size_t ws_size,
                              hipStream_t stream)
{
  (void)in_sizes; (void)n_in; (void)out_size; (void)ws_size;
  const float* x     = (const float*)d_in[0];
  const float* Wq    = (const float*)d_in[1];
  const float* Wk    = (const float*)d_in[2];
  const float* Wv    = (const float*)d_in[3];
  const float* Wo    = (const float*)d_in[4];
  const float* theta = (const float*)d_in[5];
  const float* Wcq   = (const float*)d_in[6];
  const float* ln1g  = (const float*)d_in[7];
  const float* ln1b  = (const float*)d_in[8];
  const float* W1    = (const float*)d_in[9];
  const float* b1    = (const float*)d_in[10];
  const float* W2    = (const float*)d_in[11];
  const float* b2    = (const float*)d_in[12];
  const float* ln2g  = (const float*)d_in[13];
  const float* ln2b  = (const float*)d_in[14];

  // workspace layout (lifetime-aliased, 186 MB total)
  char* ws = (char*)d_ws;
  const size_t MB = 1ull << 20;
  bf16_t* xbf    = (bf16_t*)(ws + 0);          // 16MB: x bf16, later x1 (post-LN1)
  bf16_t* QKV    = (bf16_t*)(ws + 16 * MB);    // 48MB: q|k|v
  float*  preLN1 = (float*)(ws + 16 * MB);     // 32MB alias (QKV dead after attn)
  bf16_t* A2     = (bf16_t*)(ws + 64 * MB);    // 32MB: [ctx | qh]
  float*  preLN2 = (float*)(ws + 64 * MB);     // 32MB alias (A2 dead after gemm1)
  bf16_t* H1     = (bf16_t*)(ws + 96 * MB);    // 64MB: FFN hidden
  bf16_t* BtQKV  = (bf16_t*)(ws + 160 * MB);   // 6MB: [Wq;Wk;Wv]^T  [3072][1024]
  bf16_t* Bt2    = (bf16_t*)(ws + 166 * MB);   // 4MB: [Wo|Wcq]^T    [1024][2048]
  bf16_t* BtW1   = (bf16_t*)(ws + 170 * MB);   // 8MB: W1^T          [4096][1024]
  bf16_t* BtW2   = (bf16_t*)(ws + 178 * MB);   // 8MB: W2^T          [1024][4096]

  dim3 tb(32, 8);
  prep_x_kernel<<<4096, 256, 0, stream>>>(x, theta, xbf, A2);
  transpose_w_kernel<<<dim3(32, 32), tb, 0, stream>>>(Wq,  BtQKV,              1024, 1024, 0);
  transpose_w_kernel<<<dim3(32, 32), tb, 0, stream>>>(Wk,  BtQKV + 1024*1024,  1024, 1024, 0);
  transpose_w_kernel<<<dim3(32, 32), tb, 0, stream>>>(Wv,  BtQKV + 2048*1024,  1024, 1024, 0);
  transpose_w_kernel<<<dim3(32, 32), tb, 0, stream>>>(Wo,  Bt2,  1024, 2048, 0);
  transpose_w_kernel<<<dim3(32, 32), tb, 0, stream>>>(Wcq, Bt2,  1024, 2048, 1024);
  transpose_w_kernel<<<dim3(128, 32), tb, 0, stream>>>(W1, BtW1, 4096, 1024, 0);
  transpose_w_kernel<<<dim3(32, 128), tb, 0, stream>>>(W2, BtW2, 1024, 4096, 0);

  // 1) QKV projection
  gemm_bt<0><<<dim3(24, 64), 256, 0, stream>>>(xbf, BtQKV, QKV, 8192, 3072, 1024, nullptr, nullptr);
  // 2) flash attention -> ctx (left half of A2)
  attn_kernel<<<dim3(64, 16), 256, 0, stream>>>(QKV, A2);
  // 3) fused attn-out: 0.5*([ctx|qh] @ [Wo;Wcq]) + x -> preLN1
  gemm_bt<1><<<dim3(8, 64), 256, 0, stream>>>(A2, Bt2, preLN1, 8192, 1024, 2048, x, nullptr);
  // 4) LN1 -> x1 (bf16)
  ln_bf16_kernel<<<8192, 256, 0, stream>>>(preLN1, ln1g, ln1b, xbf);
  // 5) FFN1: relu(x1@W1 + b1) -> H1
  gemm_bt<2><<<dim3(32, 64), 256, 0, stream>>>(xbf, BtW1, H1, 8192, 4096, 1024, b1, nullptr);
  // 6) FFN2: H1@W2 + b2 + x1 -> preLN2
  gemm_bt<3><<<dim3(8, 64), 256, 0, stream>>>(H1, BtW2, preLN2, 8192, 1024, 4096, b2, xbf);
  // 7) LN2 -> output (f32)
  ln_f32_kernel<<<8192, 256, 0, stream>>>(preLN2, ln2g, ln2b, (float*)d_out);
}